// Round 13
// baseline (440.463 us; speedup 1.0000x reference)
//
#include <hip/hip_runtime.h>

#define NEMBD 2048
#define ROW4 (NEMBD / 4)    // 512 float4 per token row
#define NEXP 8
#define W4N (NEXP * ROW4)   // 4096 float4 = 64 KB

__device__ __forceinline__ float dot4(float4 a, float4 b) {
    return a.x * b.x + a.y * b.y + a.z * b.z + a.w * b.w;
}

// Load one half (4 chunks) of two consecutive token rows into registers.
__device__ __forceinline__ void issue_loads(const float4* __restrict__ X4,
        float4 (&X)[8], int t0, int h, int lane, int ntok) {
    const float4 z4 = make_float4(0.f, 0.f, 0.f, 0.f);
    const bool v0 = t0 < ntok, v1 = (t0 + 1) < ntok;
    #pragma unroll
    for (int c = 0; c < 4; ++c) {
        const int col = (h * 4 + c) * 64 + lane;
        X[c]     = v0 ? X4[(size_t)t0 * ROW4 + col] : z4;
        X[4 + c] = v1 ? X4[(size_t)(t0 + 1) * ROW4 + col] : z4;
    }
}

// FMA one half (4 chunks x 8 experts) from LDS-resident W.
__device__ __forceinline__ void compute_half(const float4* __restrict__ Wl,
        const float4 (&X)[8], float (&a)[16], int h, int lane) {
    #pragma unroll
    for (int c = 0; c < 4; ++c) {
        const int col = (h * 4 + c) * 64 + lane;
        #pragma unroll
        for (int e = 0; e < 8; ++e) {
            float4 wv = Wl[e * ROW4 + col];
            a[e]     += dot4(X[c], wv);
            a[8 + e] += dot4(X[4 + c], wv);
        }
    }
}

// Verified epilogue: butterfly distribute, softmax, top-2, store, aux.
__device__ __forceinline__ void finish_group(float (&a)[16], int t0, int lane,
        int ntok, float* __restrict__ out_p, float* __restrict__ out_i,
        float& imp_acc, float& load_acc) {
    // Two pure butterfly steps collapse the 4 lanes sharing (lane mod 16);
    // four split steps distribute so lane l holds the full logit for
    // accumulator index (l & 15): token t0 + ((l>>3)&1), expert (l&7).
    #pragma unroll
    for (int q = 0; q < 16; ++q) a[q] += __shfl_xor(a[q], 32, 64);
    #pragma unroll
    for (int q = 0; q < 16; ++q) a[q] += __shfl_xor(a[q], 16, 64);
    #pragma unroll
    for (int s = 0; s < 4; ++s) {
        const int hm = 8 >> s;
        const bool hi = (lane & hm) != 0;
        #pragma unroll
        for (int q = 0; q < 8; ++q) {
            if (q < hm) {
                float send = hi ? a[q] : a[q + hm];
                float recv = __shfl_xor(send, hm, 64);
                float keep = hi ? a[q + hm] : a[q];
                a[q] = keep + recv;
            }
        }
    }
    const float logit = a[0];
    const int e = lane & 7;
    const int k = (lane >> 3) & 1;
    const bool tvalid = (t0 + k) < ntok;

    // Softmax across the 8-lane expert group.
    float m = logit;
    #pragma unroll
    for (int mm = 1; mm <= 4; mm <<= 1) m = fmaxf(m, __shfl_xor(m, mm, 64));
    float p = __expf(logit - m);
    float ssum = p;
    #pragma unroll
    for (int mm = 1; mm <= 4; mm <<= 1) ssum += __shfl_xor(ssum, mm, 64);
    const float prob = p / ssum;

    // Top-2 butterfly merge (lower index wins ties — matches jax.lax.top_k
    // / argmax first-occurrence semantics).
    float v1 = prob, v2 = -1.f;
    int   i1 = e,    i2 = -1;
    #pragma unroll
    for (int mm = 1; mm <= 4; mm <<= 1) {
        float b1 = __shfl_xor(v1, mm, 64);
        float b2 = __shfl_xor(v2, mm, 64);
        int  bi1 = __shfl_xor(i1, mm, 64);
        int  bi2 = __shfl_xor(i2, mm, 64);
        bool aw = (v1 > b1) || (v1 == b1 && i1 < bi1);
        float w1 = aw ? v1 : b1;  int wi1 = aw ? i1 : bi1;
        float l1 = aw ? b1 : v1;  int li1 = aw ? bi1 : i1;
        float w2 = aw ? v2 : b2;  int wi2 = aw ? i2 : bi2;
        bool sw = (l1 > w2) || (l1 == w2 && li1 < wi2);
        v1 = w1; i1 = wi1;
        v2 = sw ? l1 : w2;  i2 = sw ? li1 : wi2;
    }

    if (e == 0 && lane < 16 && tvalid) {
        const int t = t0 + k;
        const float denom = v1 + v2;
        out_p[2 * t]     = v1 / denom;
        out_p[2 * t + 1] = v2 / denom;
        out_i[2 * t]     = (float)i1;
        out_i[2 * t + 1] = (float)i2;
    }

    // Aux-loss partials: xor-8 sums the wave's 2 tokens; lanes l and l^8
    // both end with per-expert (l&7) sums.
    float pc = tvalid ? prob : 0.f;
    float oc = (tvalid && e == i1) ? 1.f : 0.f;
    pc += __shfl_xor(pc, 8, 64);
    oc += __shfl_xor(oc, 8, 64);
    imp_acc  += pc;
    load_acc += oc;
}

// Block = 512 threads = 8 waves; 512 blocks -> 2 blocks/CU, ALL waves
// resident (16/CU). Each wave: 2 groups x 2 tokens, software-pipelined in
// 4-chunk half-phases with two 8xfloat4 register buffers (64 VGPRs, not
// the 128 that spilled in R9). W staged once per block in LDS (64 KB).
__global__ __launch_bounds__(512, 4) void gate_kernel(
    const float* __restrict__ x, const float* __restrict__ W,
    float* __restrict__ out, float* __restrict__ ws, int ntok)
{
    __shared__ float4 Wl[W4N];          // exactly 64 KB

    const int tid  = threadIdx.x;
    const int lane = tid & 63;
    const int wid  = tid >> 6;          // 0..7

    const float4* X4 = (const float4*)x;
    const float4* W4 = (const float4*)W;
    float* out_p = out;                 // [ntok][2] renormalized top-2 probs
    float* out_i = out + 2 * ntok;      // [ntok][2] indices (as float)

    const int tb  = blockIdx.x * 32;
    const int tg0 = tb + wid * 2;       // group-0 tokens (t, t+1)
    const int tg1 = tb + 16 + wid * 2;  // group-1 tokens

    float4 XA[8], XB[8];
    float a[16];
    float imp_acc = 0.f, load_acc = 0.f;

    // Prologue: issue group-0 first-half loads, then stage W under them.
    issue_loads(X4, XA, tg0, 0, lane, ntok);
    #pragma unroll
    for (int k2 = 0; k2 < 8; ++k2)
        Wl[tid + k2 * 512] = W4[tid + k2 * 512];
    __syncthreads();

    issue_loads(X4, XB, tg0, 1, lane, ntok);
    __builtin_amdgcn_sched_barrier(0);

    #pragma unroll
    for (int q = 0; q < 16; ++q) a[q] = 0.f;
    compute_half(Wl, XA, a, 0, lane);           // consumes XA (g0 h0)
    __builtin_amdgcn_sched_barrier(0);

    issue_loads(X4, XA, tg1, 0, lane, ntok);    // prefetch g1 h0 into XA
    __builtin_amdgcn_sched_barrier(0);

    compute_half(Wl, XB, a, 1, lane);           // consumes XB (g0 h1)
    finish_group(a, tg0, lane, ntok, out_p, out_i, imp_acc, load_acc);
    __builtin_amdgcn_sched_barrier(0);

    issue_loads(X4, XB, tg1, 1, lane, ntok);    // prefetch g1 h1 into XB
    __builtin_amdgcn_sched_barrier(0);

    #pragma unroll
    for (int q = 0; q < 16; ++q) a[q] = 0.f;
    compute_half(Wl, XA, a, 0, lane);           // g1 h0
    compute_half(Wl, XB, a, 1, lane);           // g1 h1
    finish_group(a, tg1, lane, ntok, out_p, out_i, imp_acc, load_acc);

    // Per-block partial reduction; reuse the W LDS region (reads done).
    float* part = (float*)Wl;                   // [8 waves][16]
    __syncthreads();                            // all W reads complete
    if (lane < 8)       part[wid * 16 + lane] = imp_acc;       // imp[e]
    else if (lane < 16) part[wid * 16 + lane] = load_acc;      // load[e]
    __syncthreads();
    if (tid < 16) {
        float v = 0.f;
        #pragma unroll
        for (int w = 0; w < 8; ++w) v += part[w * 16 + tid];
        ws[blockIdx.x * 16 + tid] = v;
    }
}

__global__ void finalize_kernel(const float* __restrict__ ws,
                                float* __restrict__ out, int nblk, int ntok)
{
    __shared__ float s[16][16];
    __shared__ float tot[16];
    const int t = threadIdx.x;
    const int slot = t & 15, chunk = t >> 4;
    float p = 0.f;
    for (int b = chunk; b < nblk; b += 16) p += ws[b * 16 + slot];
    s[chunk][slot] = p;
    __syncthreads();
    if (t < 16) {
        float v = 0.f;
        #pragma unroll
        for (int c = 0; c < 16; ++c) v += s[c][t];
        tot[t] = v;
    }
    __syncthreads();
    if (t == 0) {
        const float inv = 1.f / (float)ntok;
        float aux = 0.f;
        #pragma unroll
        for (int e = 0; e < 8; ++e)
            aux += (tot[e] * inv) * (tot[8 + e] * inv);
        out[4 * ntok] = 8.f * aux * 0.01f;
    }
}

extern "C" void kernel_launch(void* const* d_in, const int* in_sizes, int n_in,
                              void* d_out, int out_size, void* d_ws, size_t ws_size,
                              hipStream_t stream)
{
    const float* x = (const float*)d_in[0];
    const float* W = (const float*)d_in[1];
    const int ntok    = in_sizes[0] / NEMBD;    // 16384
    const int nblocks = (ntok + 31) / 32;       // 512 blocks x 8 waves

    gate_kernel<<<nblocks, 512, 0, stream>>>(
        x, W, (float*)d_out, (float*)d_ws, ntok);
    finalize_kernel<<<1, 256, 0, stream>>>(
        (const float*)d_ws, (float*)d_out, nblocks, ntok);
}

// Round 17
// 301.680 us; speedup vs baseline: 1.4600x; 1.4600x over previous
//
#include <hip/hip_runtime.h>

#define NEMBD 2048
#define ROW4 (NEMBD / 4)    // 512 float4 per token row
#define NEXP 8
#define W4N (NEXP * ROW4)   // 4096 float4 = 64 KB

__device__ __forceinline__ float dot4(float4 a, float4 b) {
    return a.x * b.x + a.y * b.y + a.z * b.z + a.w * b.w;
}

// Load one half (4 chunks) of two consecutive token rows into registers.
__device__ __forceinline__ void issue_loads(const float4* __restrict__ X4,
        float4 (&X)[8], int t0, int h, int lane, int ntok) {
    const float4 z4 = make_float4(0.f, 0.f, 0.f, 0.f);
    const bool v0 = t0 < ntok, v1 = (t0 + 1) < ntok;
    #pragma unroll
    for (int c = 0; c < 4; ++c) {
        const int col = (h * 4 + c) * 64 + lane;
        X[c]     = v0 ? X4[(size_t)t0 * ROW4 + col] : z4;
        X[4 + c] = v1 ? X4[(size_t)(t0 + 1) * ROW4 + col] : z4;
    }
}

// FMA one half (4 chunks x 8 experts) from LDS-resident W.
__device__ __forceinline__ void compute_half(const float4* __restrict__ Wl,
        const float4 (&X)[8], float (&a)[16], int h, int lane) {
    #pragma unroll
    for (int c = 0; c < 4; ++c) {
        const int col = (h * 4 + c) * 64 + lane;
        #pragma unroll
        for (int e = 0; e < 8; ++e) {
            float4 wv = Wl[e * ROW4 + col];
            a[e]     += dot4(X[c], wv);
            a[8 + e] += dot4(X[4 + c], wv);
        }
    }
}

// Verified epilogue: butterfly distribute, softmax, top-2, store, aux.
__device__ __forceinline__ void finish_group(float (&a)[16], int t0, int lane,
        int ntok, float* __restrict__ out_p, float* __restrict__ out_i,
        float& imp_acc, float& load_acc) {
    // Two pure butterfly steps collapse the 4 lanes sharing (lane mod 16);
    // four split steps distribute so lane l holds the full logit for
    // accumulator index (l & 15): token t0 + ((l>>3)&1), expert (l&7).
    #pragma unroll
    for (int q = 0; q < 16; ++q) a[q] += __shfl_xor(a[q], 32, 64);
    #pragma unroll
    for (int q = 0; q < 16; ++q) a[q] += __shfl_xor(a[q], 16, 64);
    #pragma unroll
    for (int s = 0; s < 4; ++s) {
        const int hm = 8 >> s;
        const bool hi = (lane & hm) != 0;
        #pragma unroll
        for (int q = 0; q < 8; ++q) {
            if (q < hm) {
                float send = hi ? a[q] : a[q + hm];
                float recv = __shfl_xor(send, hm, 64);
                float keep = hi ? a[q + hm] : a[q];
                a[q] = keep + recv;
            }
        }
    }
    const float logit = a[0];
    const int e = lane & 7;
    const int k = (lane >> 3) & 1;
    const bool tvalid = (t0 + k) < ntok;

    // Softmax across the 8-lane expert group.
    float m = logit;
    #pragma unroll
    for (int mm = 1; mm <= 4; mm <<= 1) m = fmaxf(m, __shfl_xor(m, mm, 64));
    float p = __expf(logit - m);
    float ssum = p;
    #pragma unroll
    for (int mm = 1; mm <= 4; mm <<= 1) ssum += __shfl_xor(ssum, mm, 64);
    const float prob = p / ssum;

    // Top-2 butterfly merge (lower index wins ties — matches jax.lax.top_k
    // / argmax first-occurrence semantics).
    float v1 = prob, v2 = -1.f;
    int   i1 = e,    i2 = -1;
    #pragma unroll
    for (int mm = 1; mm <= 4; mm <<= 1) {
        float b1 = __shfl_xor(v1, mm, 64);
        float b2 = __shfl_xor(v2, mm, 64);
        int  bi1 = __shfl_xor(i1, mm, 64);
        int  bi2 = __shfl_xor(i2, mm, 64);
        bool aw = (v1 > b1) || (v1 == b1 && i1 < bi1);
        float w1 = aw ? v1 : b1;  int wi1 = aw ? i1 : bi1;
        float l1 = aw ? b1 : v1;  int li1 = aw ? bi1 : i1;
        float w2 = aw ? v2 : b2;  int wi2 = aw ? i2 : bi2;
        bool sw = (l1 > w2) || (l1 == w2 && li1 < wi2);
        v1 = w1; i1 = wi1;
        v2 = sw ? l1 : w2;  i2 = sw ? li1 : wi2;
    }

    if (e == 0 && lane < 16 && tvalid) {
        const int t = t0 + k;
        const float denom = v1 + v2;
        out_p[2 * t]     = v1 / denom;
        out_p[2 * t + 1] = v2 / denom;
        out_i[2 * t]     = (float)i1;
        out_i[2 * t + 1] = (float)i2;
    }

    // Aux-loss partials: xor-8 sums the wave's 2 tokens; lanes l and l^8
    // both end with per-expert (l&7) sums.
    float pc = tvalid ? prob : 0.f;
    float oc = (tvalid && e == i1) ? 1.f : 0.f;
    pc += __shfl_xor(pc, 8, 64);
    oc += __shfl_xor(oc, 8, 64);
    imp_acc  += pc;
    load_acc += oc;
}

// Block = 512 threads = 8 waves; 512 blocks. Plain __launch_bounds__(512):
// R9 showed this yields a 128-VGPR cap (4 waves/SIMD, 16 waves/CU, and
// 2 blocks/CU by LDS). R13's (512,4) crushed the cap to 64 and spilled
// 525 MB — this kernel's ~104-VGPR ping-pong design needs the 128 cap.
// Each wave: 2 groups x 2 tokens, software-pipelined in 4-chunk
// half-phases with two 8xfloat4 register buffers. W staged once in LDS.
__global__ __launch_bounds__(512) void gate_kernel(
    const float* __restrict__ x, const float* __restrict__ W,
    float* __restrict__ out, float* __restrict__ ws, int ntok)
{
    __shared__ float4 Wl[W4N];          // exactly 64 KB

    const int tid  = threadIdx.x;
    const int lane = tid & 63;
    const int wid  = tid >> 6;          // 0..7

    const float4* X4 = (const float4*)x;
    const float4* W4 = (const float4*)W;
    float* out_p = out;                 // [ntok][2] renormalized top-2 probs
    float* out_i = out + 2 * ntok;      // [ntok][2] indices (as float)

    const int tb  = blockIdx.x * 32;
    const int tg0 = tb + wid * 2;       // group-0 tokens (t, t+1)
    const int tg1 = tb + 16 + wid * 2;  // group-1 tokens

    float4 XA[8], XB[8];
    float a[16];
    float imp_acc = 0.f, load_acc = 0.f;

    // Prologue: issue group-0 first-half loads, then stage W under them.
    issue_loads(X4, XA, tg0, 0, lane, ntok);
    #pragma unroll
    for (int k2 = 0; k2 < 8; ++k2)
        Wl[tid + k2 * 512] = W4[tid + k2 * 512];
    __syncthreads();

    issue_loads(X4, XB, tg0, 1, lane, ntok);
    __builtin_amdgcn_sched_barrier(0);

    #pragma unroll
    for (int q = 0; q < 16; ++q) a[q] = 0.f;
    compute_half(Wl, XA, a, 0, lane);           // consumes XA (g0 h0)
    __builtin_amdgcn_sched_barrier(0);

    issue_loads(X4, XA, tg1, 0, lane, ntok);    // prefetch g1 h0 into XA
    __builtin_amdgcn_sched_barrier(0);

    compute_half(Wl, XB, a, 1, lane);           // consumes XB (g0 h1)
    finish_group(a, tg0, lane, ntok, out_p, out_i, imp_acc, load_acc);
    __builtin_amdgcn_sched_barrier(0);

    issue_loads(X4, XB, tg1, 1, lane, ntok);    // prefetch g1 h1 into XB
    __builtin_amdgcn_sched_barrier(0);

    #pragma unroll
    for (int q = 0; q < 16; ++q) a[q] = 0.f;
    compute_half(Wl, XA, a, 0, lane);           // g1 h0
    compute_half(Wl, XB, a, 1, lane);           // g1 h1
    finish_group(a, tg1, lane, ntok, out_p, out_i, imp_acc, load_acc);

    // Per-block partial reduction; reuse the W LDS region (reads done).
    float* part = (float*)Wl;                   // [8 waves][16]
    __syncthreads();                            // all W reads complete
    if (lane < 8)       part[wid * 16 + lane] = imp_acc;       // imp[e]
    else if (lane < 16) part[wid * 16 + lane] = load_acc;      // load[e]
    __syncthreads();
    if (tid < 16) {
        float v = 0.f;
        #pragma unroll
        for (int w = 0; w < 8; ++w) v += part[w * 16 + tid];
        ws[blockIdx.x * 16 + tid] = v;
    }
}

__global__ void finalize_kernel(const float* __restrict__ ws,
                                float* __restrict__ out, int nblk, int ntok)
{
    __shared__ float s[16][16];
    __shared__ float tot[16];
    const int t = threadIdx.x;
    const int slot = t & 15, chunk = t >> 4;
    float p = 0.f;
    for (int b = chunk; b < nblk; b += 16) p += ws[b * 16 + slot];
    s[chunk][slot] = p;
    __syncthreads();
    if (t < 16) {
        float v = 0.f;
        #pragma unroll
        for (int c = 0; c < 16; ++c) v += s[c][t];
        tot[t] = v;
    }
    __syncthreads();
    if (t == 0) {
        const float inv = 1.f / (float)ntok;
        float aux = 0.f;
        #pragma unroll
        for (int e = 0; e < 8; ++e)
            aux += (tot[e] * inv) * (tot[8 + e] * inv);
        out[4 * ntok] = 8.f * aux * 0.01f;
    }
}

extern "C" void kernel_launch(void* const* d_in, const int* in_sizes, int n_in,
                              void* d_out, int out_size, void* d_ws, size_t ws_size,
                              hipStream_t stream)
{
    const float* x = (const float*)d_in[0];
    const float* W = (const float*)d_in[1];
    const int ntok    = in_sizes[0] / NEMBD;    // 16384
    const int nblocks = (ntok + 31) / 32;       // 512 blocks x 8 waves

    gate_kernel<<<nblocks, 512, 0, stream>>>(
        x, W, (float*)d_out, (float*)d_ws, ntok);
    finalize_kernel<<<1, 256, 0, stream>>>(
        (const float*)d_ws, (float*)d_out, nblocks, ntok);
}